// Round 1
// baseline (478.620 us; speedup 1.0000x reference)
//
#include <hip/hip_runtime.h>
#include <math.h>

#define D      128
#define S_LEN  64
#define B_SZ   512
#define NH     4
#define DH     32
#define NB     2
#define VOCAB  9
#define EPS    1e-5f
#define NTOK   (B_SZ * S_LEN)

// ---------------------------------------------------------------------------
// Kernel 1: h = emb[x]; write h and per-token LN1 stats (mu, rstd).
// ln1_w is folded into Wg inside the scan kernel, so only stats are needed.
// One wave per token, 8 tokens per wave, 256 threads/block.
// ---------------------------------------------------------------------------
__global__ __launch_bounds__(256) void k_embed(const int* __restrict__ x,
                                               const float* __restrict__ emb,
                                               float* __restrict__ h,
                                               float* __restrict__ stats)
{
    int lane = threadIdx.x & 63;
    int wv   = threadIdx.x >> 6;
    int tok0 = (blockIdx.x * 4 + wv) * 8;
    for (int i = 0; i < 8; ++i) {
        int tok = tok0 + i;
        int xi  = x[tok];
        float v1 = emb[xi * D + lane];
        float v2 = emb[xi * D + 64 + lane];
        h[(size_t)tok * D + lane]      = v1;
        h[(size_t)tok * D + 64 + lane] = v2;
        float s1 = v1 + v2;
        float s2 = v1 * v1 + v2 * v2;
        #pragma unroll
        for (int d2 = 1; d2 < 64; d2 <<= 1) {
            s1 += __shfl_xor(s1, d2, 64);
            s2 += __shfl_xor(s2, d2, 64);
        }
        float mu  = s1 * (1.0f / D);
        float var = s2 * (1.0f / D) - mu * mu;
        if (lane == 0) {
            stats[tok * 2]     = mu;
            stats[tok * 2 + 1] = rsqrtf(var + EPS);
        }
    }
}

// ---------------------------------------------------------------------------
// Kernel 2: sLSTM scan + groupnorm + residual, one wave per (b, head).
// Lane j (j in 0..63): hh = j&31, half = j>>5.
//   half==0 lanes own gates (i, z) for element hh; half==1 own (f, o).
// Weights Wg (with ln1_w folded) and R columns live in VGPRs.
// h state is wave-uniform: broadcast via v_readlane into scalar regs.
// ---------------------------------------------------------------------------
__global__ __launch_bounds__(256, 2) void k_scan(const float* __restrict__ Wg,   // (4,NH,DH,DH)
                                                 const float* __restrict__ Rm,   // (NH,DH,4*DH)
                                                 const float* __restrict__ bias, // (NH,4,DH)
                                                 const float* __restrict__ gnw,  // (D)
                                                 const float* __restrict__ lnw,  // (D)
                                                 float* __restrict__ h,          // (B*S, D) in/out
                                                 const float* __restrict__ stats)// (B*S, 2)
{
    int b    = blockIdx.x;
    int n    = threadIdx.x >> 6;   // head (4 waves per block)
    int lane = threadIdx.x & 63;
    int hh   = lane & 31;
    int half = lane >> 5;
    int gA   = half;               // 0: i-gate, 1: f-gate
    int gB   = half + 2;           // 2: z-gate, 3: o-gate

    float WA[DH], WB[DH], RA[DH], RB[DH];
    float cA = 0.f, cB = 0.f;
    {
        const float* lw = lnw + n * DH;
        const float* wa = Wg + ((gA * NH + n) * DH + hh) * DH;
        const float* wb = Wg + ((gB * NH + n) * DH + hh) * DH;
        #pragma unroll
        for (int i = 0; i < DH; ++i) {
            WA[i] = wa[i] * lw[i]; cA += WA[i];
            WB[i] = wb[i] * lw[i]; cB += WB[i];
        }
        int kA = gA * DH + hh, kB = gB * DH + hh;
        #pragma unroll
        for (int i = 0; i < DH; ++i) {
            RA[i] = Rm[(n * DH + i) * (4 * DH) + kA];
            RB[i] = Rm[(n * DH + i) * (4 * DH) + kB];
        }
    }
    float bA = bias[(n * 4 + gA) * DH + hh];
    float bB = bias[(n * 4 + gB) * DH + hh];
    float gw = gnw[n * DH + hh];

    float hu[DH];
    #pragma unroll
    for (int i = 0; i < DH; ++i) hu[i] = 0.f;
    float c = 0.f, nacc = 0.f, m = 0.f;

    float* hb = h + ((size_t)b * S_LEN) * D + n * DH;
    const float* st = stats + (size_t)b * S_LEN * 2;

    float4 xq[8];
    #pragma unroll
    for (int j = 0; j < 8; ++j) xq[j] = ((const float4*)hb)[j];

    #pragma unroll 2
    for (int s = 0; s < S_LEN; ++s) {
        float* hp = hb + s * D;
        // prefetch next step's h slice (pre-residual rows; rows are disjoint)
        int sp = (s + 1 < S_LEN) ? (s + 1) : s;
        float4 xqn[8];
        #pragma unroll
        for (int j = 0; j < 8; ++j) xqn[j] = ((const float4*)(hb + sp * D))[j];

        float mu_t = st[s * 2];
        float rs_t = st[s * 2 + 1];

        const float* xv = (const float*)xq;
        float d0 = 0, d1 = 0, d2 = 0, d3 = 0, e0 = 0, e1 = 0, e2 = 0, e3 = 0;
        #pragma unroll
        for (int i = 0; i < DH; i += 4) {
            d0 = fmaf(xv[i],     WA[i],     d0);
            d1 = fmaf(xv[i + 1], WA[i + 1], d1);
            d2 = fmaf(xv[i + 2], WA[i + 2], d2);
            d3 = fmaf(xv[i + 3], WA[i + 3], d3);
            e0 = fmaf(xv[i],     WB[i],     e0);
            e1 = fmaf(xv[i + 1], WB[i + 1], e1);
            e2 = fmaf(xv[i + 2], WB[i + 2], e2);
            e3 = fmaf(xv[i + 3], WB[i + 3], e3);
        }
        float gxa = rs_t * (((d0 + d1) + (d2 + d3)) - mu_t * cA);
        float gxb = rs_t * (((e0 + e1) + (e2 + e3)) - mu_t * cB);

        float r0 = 0, r1 = 0, r2 = 0, r3 = 0, q0 = 0, q1 = 0, q2 = 0, q3 = 0;
        #pragma unroll
        for (int i = 0; i < DH; i += 4) {
            r0 = fmaf(hu[i],     RA[i],     r0);
            r1 = fmaf(hu[i + 1], RA[i + 1], r1);
            r2 = fmaf(hu[i + 2], RA[i + 2], r2);
            r3 = fmaf(hu[i + 3], RA[i + 3], r3);
            q0 = fmaf(hu[i],     RB[i],     q0);
            q1 = fmaf(hu[i + 1], RB[i + 1], q1);
            q2 = fmaf(hu[i + 2], RB[i + 2], q2);
            q3 = fmaf(hu[i + 3], RB[i + 3], q3);
        }
        float rawA = gxa + ((r0 + r1) + (r2 + r3)) + bA;
        float rawB = gxb + ((q0 + q1) + (q2 + q3)) + bB;

        float oA = __shfl_xor(rawA, 32, 64);
        float oB = __shfl_xor(rawB, 32, 64);
        float i_r = half ? oA : rawA;
        float f_r = half ? rawA : oA;
        float z_r = half ? oB : rawB;
        float o_r = half ? rawB : oB;

        // log_sigmoid(f) = min(f,0) - log1p(exp(-|f|))
        float lsf  = fminf(f_r, 0.f) - log1pf(expf(-fabsf(f_r)));
        float lfm  = m + lsf;
        float mnew = fmaxf(i_r, lfm);
        float ig   = expf(i_r - mnew);
        float fg   = expf(lfm - mnew);
        float tm   = expm1f(2.f * z_r);          // tanh(z) = t/(t+2), stable both ends
        float tz   = tm / (tm + 2.f);
        c    = fg * c + ig * tz;
        nacc = fg * nacc + ig;
        m    = mnew;
        float so = 1.f / (1.f + expf(-o_r));
        float hv = so * c / nacc;

        // groupnorm over DH (halves hold identical copies -> reduce 1..16 only)
        float s1 = hv, s2 = hv * hv;
        #pragma unroll
        for (int d5 = 1; d5 < 32; d5 <<= 1) {
            s1 += __shfl_xor(s1, d5, 64);
            s2 += __shfl_xor(s2, d5, 64);
        }
        float mu  = s1 * (1.0f / DH);
        float var = s2 * (1.0f / DH) - mu * mu;
        float hn  = (hv - mu) * rsqrtf(var + EPS) * gw;

        float hres = hp[hh];
        if (half == 0) hp[hh] = hres + hn;   // residual write (h_mid)

        // broadcast new h to wave-uniform regs
        #pragma unroll
        for (int i = 0; i < DH; ++i)
            hu[i] = __int_as_float(__builtin_amdgcn_readlane(__float_as_int(hv), i));

        #pragma unroll
        for (int j = 0; j < 8; ++j) xq[j] = xqn[j];
    }
}

// XOR swizzle on the float4-column bits to decorrelate LDS banks across rows.
__device__ __forceinline__ int xc2(int t, int ci) {
    return ci ^ (((t >> 2) & 3) << 2);
}

// ---------------------------------------------------------------------------
// Kernel 3: fused LN2 -> up GEMM -> exact GeLU -> down GEMM -> residual ->
//           (LAST=0: write h and next-layer LN1 stats | LAST=1: post-LN + proj)
// 64 tokens per block, 256 threads, 4x4 register tile, 64 KiB static LDS.
// ---------------------------------------------------------------------------
template <int LAST>
__global__ __launch_bounds__(256, 2) void k_ff(float* __restrict__ h,            // (B*S, D) in/out
                                               const float* __restrict__ ln2w,   // (D)
                                               const float* __restrict__ wup,    // (2D, D)
                                               const float* __restrict__ wdn,    // (D, D)
                                               float* __restrict__ stats_out,    // (B*S,2)  LAST=0
                                               const float* __restrict__ lastw,  // post_w   LAST=1
                                               const float* __restrict__ projw,  // (VOCAB,D)
                                               const float* __restrict__ projb,  // (VOCAB)
                                               float* __restrict__ out)          // (B*S,VOCAB)
{
    __shared__ float xs[64 * 128];      // xn (later: hnew stash)
    __shared__ float as_[64 * 64];      // act half-tile
    __shared__ float wt[2 * 32 * 64];   // weight tiles [slot][kk][o]

    int tid  = threadIdx.x;
    int lane = tid & 63;
    int wv   = tid >> 6;
    size_t tok0 = (size_t)blockIdx.x * 64;

    // ---- phase 1: LN2 into xs ----
    for (int i = 0; i < 16; ++i) {
        int t = wv * 16 + i;
        const float* hp = h + (tok0 + t) * D;
        float v1 = hp[lane], v2 = hp[64 + lane];
        float s1 = v1 + v2, s2 = v1 * v1 + v2 * v2;
        #pragma unroll
        for (int d2 = 1; d2 < 64; d2 <<= 1) {
            s1 += __shfl_xor(s1, d2, 64);
            s2 += __shfl_xor(s2, d2, 64);
        }
        float mu = s1 * (1.0f / D);
        float rs = rsqrtf(s2 * (1.0f / D) - mu * mu + EPS);
        xs[t * D + xc2(t, lane)]      = (v1 - mu) * rs * ln2w[lane];
        xs[t * D + xc2(t, lane + 64)] = (v2 - mu) * rs * ln2w[64 + lane];
    }
    __syncthreads();

    int ti = tid >> 4;    // 0..15
    int oi = tid & 15;    // 0..15
    int t0 = ti * 4;
    int o0 = oi * 4;

    float accd[2][4][4];
    #pragma unroll
    for (int a1 = 0; a1 < 2; ++a1)
        #pragma unroll
        for (int j = 0; j < 4; ++j)
            #pragma unroll
            for (int cc = 0; cc < 4; ++cc) accd[a1][j][cc] = 0.f;

    #pragma unroll
    for (int p = 0; p < 2; ++p) {
        float accg[4][4], accv[4][4];
        #pragma unroll
        for (int j = 0; j < 4; ++j)
            #pragma unroll
            for (int cc = 0; cc < 4; ++cc) { accg[j][cc] = 0.f; accv[j][cc] = 0.f; }

        // ---- UP: gate rows p*64.., value rows 128+p*64.. ----
        for (int kc = 0; kc < 128; kc += 32) {
            __syncthreads();
            {
                const float* b0 = wup + (p * 64) * D + kc;
                const float* b1 = wup + (128 + p * 64) * D + kc;
                #pragma unroll
                for (int i2 = 0; i2 < 4; ++i2) {
                    int idx = i2 * 256 + tid;
                    int slot = idx >> 9;
                    const float* basep = slot ? b1 : b0;
                    int r = (idx >> 3) & 63;
                    int q = idx & 7;
                    float4 v = *(const float4*)(basep + r * D + q * 4);
                    float* dst = wt + slot * 2048;
                    dst[(q * 4 + 0) * 64 + r] = v.x;
                    dst[(q * 4 + 1) * 64 + r] = v.y;
                    dst[(q * 4 + 2) * 64 + r] = v.z;
                    dst[(q * 4 + 3) * 64 + r] = v.w;
                }
            }
            __syncthreads();
            #pragma unroll
            for (int k4 = 0; k4 < 8; ++k4) {
                float4 av4[4];
                #pragma unroll
                for (int j = 0; j < 4; ++j)
                    av4[j] = *(const float4*)&xs[(t0 + j) * D + xc2(t0 + j, kc + k4 * 4)];
                #pragma unroll
                for (int i = 0; i < 4; ++i) {
                    float4 bg = *(const float4*)&wt[(k4 * 4 + i) * 64 + o0];
                    float4 bv = *(const float4*)&wt[2048 + (k4 * 4 + i) * 64 + o0];
                    #pragma unroll
                    for (int j = 0; j < 4; ++j) {
                        float avx = ((const float*)&av4[j])[i];
                        accg[j][0] = fmaf(avx, bg.x, accg[j][0]);
                        accg[j][1] = fmaf(avx, bg.y, accg[j][1]);
                        accg[j][2] = fmaf(avx, bg.z, accg[j][2]);
                        accg[j][3] = fmaf(avx, bg.w, accg[j][3]);
                        accv[j][0] = fmaf(avx, bv.x, accv[j][0]);
                        accv[j][1] = fmaf(avx, bv.y, accv[j][1]);
                        accv[j][2] = fmaf(avx, bv.z, accv[j][2]);
                        accv[j][3] = fmaf(avx, bv.w, accv[j][3]);
                    }
                }
            }
        }
        // act = gelu_exact(gate) * val  ->  as_ (local cols 0..63)
        #pragma unroll
        for (int j = 0; j < 4; ++j) {
            int t = t0 + j;
            float4 actv;
            float* ap = (float*)&actv;
            #pragma unroll
            for (int cc = 0; cc < 4; ++cc) {
                float g = accg[j][cc];
                float u = accv[j][cc];
                ap[cc] = 0.5f * g * (1.0f + erff(g * 0.70710678118654752f)) * u;
            }
            *(float4*)&as_[t * 64 + xc2(t, o0)] = actv;
        }
        // ---- DOWN partial over kk = p*64 .. p*64+63 ----
        for (int kc = 0; kc < 64; kc += 32) {
            __syncthreads();
            {
                const float* b0 = wdn + p * 64 + kc;
                const float* b1 = wdn + 64 * D + p * 64 + kc;
                #pragma unroll
                for (int i2 = 0; i2 < 4; ++i2) {
                    int idx = i2 * 256 + tid;
                    int slot = idx >> 9;
                    const float* basep = slot ? b1 : b0;
                    int r = (idx >> 3) & 63;
                    int q = idx & 7;
                    float4 v = *(const float4*)(basep + r * D + q * 4);
                    float* dst = wt + slot * 2048;
                    dst[(q * 4 + 0) * 64 + r] = v.x;
                    dst[(q * 4 + 1) * 64 + r] = v.y;
                    dst[(q * 4 + 2) * 64 + r] = v.z;
                    dst[(q * 4 + 3) * 64 + r] = v.w;
                }
            }
            __syncthreads();
            #pragma unroll
            for (int k4 = 0; k4 < 8; ++k4) {
                float4 av4[4];
                #pragma unroll
                for (int j = 0; j < 4; ++j)
                    av4[j] = *(const float4*)&as_[(t0 + j) * 64 + xc2(t0 + j, kc + k4 * 4)];
                #pragma unroll
                for (int i = 0; i < 4; ++i) {
                    float4 b0v = *(const float4*)&wt[(k4 * 4 + i) * 64 + o0];
                    float4 b1v = *(const float4*)&wt[2048 + (k4 * 4 + i) * 64 + o0];
                    #pragma unroll
                    for (int j = 0; j < 4; ++j) {
                        float avx = ((const float*)&av4[j])[i];
                        accd[0][j][0] = fmaf(avx, b0v.x, accd[0][j][0]);
                        accd[0][j][1] = fmaf(avx, b0v.y, accd[0][j][1]);
                        accd[0][j][2] = fmaf(avx, b0v.z, accd[0][j][2]);
                        accd[0][j][3] = fmaf(avx, b0v.w, accd[0][j][3]);
                        accd[1][j][0] = fmaf(avx, b1v.x, accd[1][j][0]);
                        accd[1][j][1] = fmaf(avx, b1v.y, accd[1][j][1]);
                        accd[1][j][2] = fmaf(avx, b1v.z, accd[1][j][2]);
                        accd[1][j][3] = fmaf(avx, b1v.w, accd[1][j][3]);
                    }
                }
            }
        }
    }

    // ---- epilogue: residual add, stash hnew in xs, write h (LAST=0) ----
    #pragma unroll
    for (int j = 0; j < 4; ++j) {
        int t = t0 + j;
        size_t tok = tok0 + t;
        #pragma unroll
        for (int a1 = 0; a1 < 2; ++a1) {
            int cb = a1 * 64 + o0;
            float4 hres = *(const float4*)(h + tok * D + cb);
            float4 hn;
            hn.x = hres.x + accd[a1][j][0];
            hn.y = hres.y + accd[a1][j][1];
            hn.z = hres.z + accd[a1][j][2];
            hn.w = hres.w + accd[a1][j][3];
            if (!LAST) *(float4*)(h + tok * D + cb) = hn;
            *(float4*)&xs[t * D + xc2(t, cb)] = hn;
        }
    }
    __syncthreads();

    // ---- final per-token phase ----
    if (!LAST) {
        for (int i = 0; i < 16; ++i) {
            int t = wv * 16 + i;
            float v1 = xs[t * D + xc2(t, lane)];
            float v2 = xs[t * D + xc2(t, lane + 64)];
            float s1 = v1 + v2, s2 = v1 * v1 + v2 * v2;
            #pragma unroll
            for (int d2 = 1; d2 < 64; d2 <<= 1) {
                s1 += __shfl_xor(s1, d2, 64);
                s2 += __shfl_xor(s2, d2, 64);
            }
            float mu = s1 * (1.0f / D);
            float rs = rsqrtf(s2 * (1.0f / D) - mu * mu + EPS);
            if (lane == 0) {
                stats_out[(tok0 + t) * 2]     = mu;
                stats_out[(tok0 + t) * 2 + 1] = rs;
            }
        }
    } else {
        float pw1[VOCAB], pw2[VOCAB], pb[VOCAB];
        #pragma unroll
        for (int v = 0; v < VOCAB; ++v) {
            pw1[v] = projw[v * D + lane];
            pw2[v] = projw[v * D + 64 + lane];
            pb[v]  = projb[v];
        }
        for (int i = 0; i < 16; ++i) {
            int t = wv * 16 + i;
            float v1 = xs[t * D + xc2(t, lane)];
            float v2 = xs[t * D + xc2(t, lane + 64)];
            float s1 = v1 + v2, s2 = v1 * v1 + v2 * v2;
            #pragma unroll
            for (int d2 = 1; d2 < 64; d2 <<= 1) {
                s1 += __shfl_xor(s1, d2, 64);
                s2 += __shfl_xor(s2, d2, 64);
            }
            float mu = s1 * (1.0f / D);
            float rs = rsqrtf(s2 * (1.0f / D) - mu * mu + EPS);
            float x1 = (v1 - mu) * rs * lastw[lane];
            float x2 = (v2 - mu) * rs * lastw[64 + lane];
            #pragma unroll
            for (int v = 0; v < VOCAB; ++v) {
                float pp = x1 * pw1[v] + x2 * pw2[v];
                #pragma unroll
                for (int d2 = 1; d2 < 64; d2 <<= 1) pp += __shfl_xor(pp, d2, 64);
                if (lane == 0) out[(tok0 + t) * VOCAB + v] = pp + pb[v];
            }
        }
    }
}

// ---------------------------------------------------------------------------
extern "C" void kernel_launch(void* const* d_in, const int* in_sizes, int n_in,
                              void* d_out, int out_size, void* d_ws, size_t ws_size,
                              hipStream_t stream)
{
    const int*   x     = (const int*)  d_in[0];
    const float* emb   = (const float*)d_in[1];
    const float* ln1   = (const float*)d_in[2];
    const float* Wg    = (const float*)d_in[3];
    const float* Rm    = (const float*)d_in[4];
    const float* bias  = (const float*)d_in[5];
    const float* gnw   = (const float*)d_in[6];
    const float* ln2   = (const float*)d_in[7];
    const float* wup   = (const float*)d_in[8];
    const float* wdn   = (const float*)d_in[9];
    const float* postw = (const float*)d_in[10];
    const float* projw = (const float*)d_in[11];
    const float* projb = (const float*)d_in[12];
    float* out   = (float*)d_out;
    float* hbuf  = (float*)d_ws;                       // (B*S, D)
    float* stats = hbuf + (size_t)NTOK * D;            // (B*S, 2)

    k_embed<<<NTOK / 32, 256, 0, stream>>>(x, emb, hbuf, stats);

    for (int bi = 0; bi < NB; ++bi) {
        k_scan<<<B_SZ, 256, 0, stream>>>(Wg + bi * 4 * NH * DH * DH,
                                         Rm + bi * NH * DH * 4 * DH,
                                         bias + bi * NH * 4 * DH,
                                         gnw + bi * D,
                                         ln1 + bi * D,
                                         hbuf, stats);
        if (bi == 0)
            k_ff<0><<<NTOK / 64, 256, 0, stream>>>(hbuf, ln2 + bi * D,
                                                   wup + bi * 2 * D * D,
                                                   wdn + bi * D * D,
                                                   stats, nullptr, nullptr,
                                                   nullptr, nullptr);
        else
            k_ff<1><<<NTOK / 64, 256, 0, stream>>>(hbuf, ln2 + bi * D,
                                                   wup + bi * 2 * D * D,
                                                   wdn + bi * D * D,
                                                   nullptr, postw, projw,
                                                   projb, out);
    }
}